// Round 3
// baseline (628.790 us; speedup 1.0000x reference)
//
#include <hip/hip_runtime.h>

using bf16   = __bf16;
using bf16x8 = __bf16 __attribute__((ext_vector_type(8)));
using f32x4  = float  __attribute__((ext_vector_type(4)));

#define NANTHRESH 64

// ---- workspace element offsets (bf16 elements) --------------------------
#define QT_OFF    0LL          // [B*N][C]      2,097,152
#define KT_OFF    2097152LL    // [B*N][4C]     8,388,608
#define V_OFF     10485760LL   // [C][B*N]      2,097,152
#define AWS_OFF   12582912LL   // [B][N][N] attn bf16 copy  8,388,608
#define AT1_OFF   20971520LL   // [4][N][N] per-b           4,194,304
#define GB_OFF    25165824LL   // [4][N][N] per-b           4,194,304
#define CW_OFF    29360128LL   // converted weights          992,464
#define FLAG_ELOFF 30352640LL  // int flag
// phase-A overlays (dead before their hosts are written):
#define CX_OFF    12582912LL   // converted x (alias AWS)
#define DWQ_OFF   14680064LL
#define DWK_OFF   16777216LL
#define DWV_OFF   18874368LL
// phase-C overlays:
#define OUTP_OFF  20971520LL   // stage-6 out [B][N][C] (alias AT1)
#define COL_OFF   0LL          // im2col [B][N][2304] (alias QT/KT/V/AWS, all dead)

__device__ __constant__ int g_nsz[20] = {
    2097152, 2304,256,65536,256, 2304,256,262144,1024,
    2304,256,65536,256, 144, 4,4,4,4, 36, 589824};
__device__ __constant__ long long g_doff[20] = {
    CX_OFF,
    CW_OFF+0,      CW_OFF+2304,   CW_OFF+2560,   CW_OFF+68096,
    CW_OFF+68352,  CW_OFF+70656,  CW_OFF+70912,  CW_OFF+333056,
    CW_OFF+334080, CW_OFF+336384, CW_OFF+336640, CW_OFF+402176,
    CW_OFF+402432, CW_OFF+402576, CW_OFF+402580, CW_OFF+402584,
    CW_OFF+402588, CW_OFF+402592, CW_OFF+402640};

struct SrcPtrs { const void* p[20]; };

__global__ void k_zero(int* p) { if (threadIdx.x < 4) p[threadIdx.x] = 0; }

// Count inf/NaN bit patterns among the first 262,144 16-bit halves of x.
// fp32 data -> low halves have random exponent field -> ~512 hits.
// bf16 N(0,1) data -> 0 hits.
__global__ __launch_bounds__(256) void k_detect(const unsigned short* __restrict__ xs,
                                                int* __restrict__ cnt)
{
    int idx = blockIdx.x * 256 + threadIdx.x;  // 64 blocks -> idx in [0,16384)
    int c = 0;
#pragma unroll
    for (int i = 0; i < 16; i++) {
        unsigned short h = xs[idx + i * 16384];
        c += ((h & 0x7F80) == 0x7F80);
    }
    if (c) atomicAdd(cnt, c);
}

// Normalize every input tensor into a bf16 ws buffer (branch on detect flag).
__global__ __launch_bounds__(256) void k_convert(SrcPtrs sp, bf16* __restrict__ wsb,
                                                 const int* __restrict__ nf)
{
    const int t = blockIdx.y;
    const int n = g_nsz[t];
    const bool srcf32 = (*nf > NANTHRESH);
    const void* src = sp.p[t];
    bf16* dst = wsb + g_doff[t];
    for (int i = blockIdx.x * 256 + threadIdx.x; i < n; i += 1024 * 256) {
        float f = srcf32 ? ((const float*)src)[i] : (float)((const bf16*)src)[i];
        if (!(fabsf(f) < 1e30f)) f = 0.f;   // sanitize NaN/Inf (diagnostic tripwire)
        dst[i] = (bf16)f;
    }
}

// ---------------------------------------------------------------------------
// Canonical NT MFMA GEMM: D[M][N] = alpha*A[M][K]@B[K][N] (+bias).
// A row-major [M][K]; Bc row-major [N][K]; D element-indexed via void* + flag.
// ---------------------------------------------------------------------------
__global__ __launch_bounds__(256) void gemm_nt(
    const bf16* __restrict__ A, const bf16* __restrict__ Bc,
    const bf16* __restrict__ bias, void* __restrict__ Dv,
    int K, int lda, int ldb, int ldd,
    int zdiv, long long sA1, long long sA2, long long sB1, long long sB2,
    long long sD1, long long sD2, float alpha, int bias_mode,
    const int* __restrict__ nf, int dyn)
{
    const int z  = blockIdx.z;
    const int zq = z / zdiv, zr = z % zdiv;
    A  += (long long)zq * sA1 + (long long)zr * sA2;
    Bc += (long long)zq * sB1 + (long long)zr * sB2;
    const long long zoff = (long long)zq * sD1 + (long long)zr * sD2;
    const bool f32o = dyn && (*nf > NANTHRESH);
    const int m0 = blockIdx.y * 64;
    const int n0 = blockIdx.x * 64;
    __shared__ __align__(16) bf16 As[64 * 72];
    __shared__ __align__(16) bf16 Bs[64 * 72];
    const int tid  = threadIdx.x;
    const int lane = tid & 63;
    const int wave = tid >> 6;
    const int wm   = (wave >> 1) * 32;
    const int wn   = (wave & 1) * 32;
    const int quad = lane >> 4;
    const int l16  = lane & 15;
    f32x4 acc[2][2] = {};
    for (int k0 = 0; k0 < K; k0 += 64) {
#pragma unroll
        for (int i = 0; i < 2; i++) {
            int cid = tid + i * 256;
            int row = cid >> 3;
            int kc  = (cid & 7) * 8;
            *reinterpret_cast<int4*>(&As[row * 72 + kc]) =
                *reinterpret_cast<const int4*>(&A[(long long)(m0 + row) * lda + k0 + kc]);
            *reinterpret_cast<int4*>(&Bs[row * 72 + kc]) =
                *reinterpret_cast<const int4*>(&Bc[(long long)(n0 + row) * ldb + k0 + kc]);
        }
        __syncthreads();
#pragma unroll
        for (int ks = 0; ks < 2; ks++) {
            bf16x8 af[2], bfr[2];
#pragma unroll
            for (int i = 0; i < 2; i++) {
                af[i]  = *reinterpret_cast<const bf16x8*>(&As[(wm + i * 16 + l16) * 72 + ks * 32 + quad * 8]);
                bfr[i] = *reinterpret_cast<const bf16x8*>(&Bs[(wn + i * 16 + l16) * 72 + ks * 32 + quad * 8]);
            }
#pragma unroll
            for (int i = 0; i < 2; i++)
#pragma unroll
                for (int j = 0; j < 2; j++)
                    acc[i][j] = __builtin_amdgcn_mfma_f32_16x16x32_bf16(af[i], bfr[j], acc[i][j], 0, 0, 0);
        }
        __syncthreads();
    }
#pragma unroll
    for (int i = 0; i < 2; i++)
#pragma unroll
        for (int j = 0; j < 2; j++)
#pragma unroll
            for (int r = 0; r < 4; r++) {
                int row = m0 + wm + i * 16 + quad * 4 + r;
                int col = n0 + wn + j * 16 + l16;
                float v = acc[i][j][r] * alpha;
                if (bias_mode == 1) v += (float)bias[row];
                else if (bias_mode == 2) v += (float)bias[col];
                long long idx = zoff + (long long)row * ldd + col;
                if (f32o) ((float*)Dv)[idx] = v;
                else      ((bf16*)Dv)[idx] = (bf16)v;
            }
}

// ---------------------------------------------------------------------------
// Depthwise 3x3 (SAME) q/k/v in one pass; outputs TRANSPOSED [b][n][c].
// ---------------------------------------------------------------------------
__global__ __launch_bounds__(256) void k_dw(
    const bf16* __restrict__ x,
    const bf16* __restrict__ wq, const bf16* __restrict__ bq,
    const bf16* __restrict__ wk, const bf16* __restrict__ bk,
    const bf16* __restrict__ wv, const bf16* __restrict__ bv,
    bf16* __restrict__ dq, bf16* __restrict__ dk, bf16* __restrict__ dv)
{
    const int blk = blockIdx.x;
    const int b = blk >> 10, hw = blk & 1023;
    const int h = hw >> 5, w = hw & 31;
    const int c = threadIdx.x;
    const bf16* xb = x + ((long long)b * 256 + c) * 1024;
    float aq = (float)bq[c], ak = (float)bk[c], av = (float)bv[c];
#pragma unroll
    for (int dh = 0; dh < 3; dh++) {
        int hh = h + dh - 1;
        if (hh < 0 || hh >= 32) continue;
#pragma unroll
        for (int dw_ = 0; dw_ < 3; dw_++) {
            int ww = w + dw_ - 1;
            if (ww < 0 || ww >= 32) continue;
            float xv = (float)xb[hh * 32 + ww];
            int wi = c * 9 + dh * 3 + dw_;
            aq += xv * (float)wq[wi];
            ak += xv * (float)wk[wi];
            av += xv * (float)wv[wi];
        }
    }
    long long o = ((long long)b * 1024 + hw) * 256 + c;
    dq[o] = (bf16)aq; dk[o] = (bf16)ak; dv[o] = (bf16)av;
}

// ---------------------------------------------------------------------------
// SINGLE-BATCH conv3x3(4->4)+BN+self-gating x*softmax(x, m-axis).
// ---------------------------------------------------------------------------
__global__ __launch_bounds__(256) void k_mid(
    const bf16* __restrict__ attn1b, const bf16* __restrict__ w0,
    const bf16* __restrict__ gamma, const bf16* __restrict__ beta,
    const bf16* __restrict__ mean,  const bf16* __restrict__ var,
    bf16* __restrict__ g)
{
    __shared__ __align__(16) bf16 sin_[12 * 1024];
    __shared__ float stt[4 * 1024];
    __shared__ float w0s[144];
    const int n = blockIdx.x;
    const int tid = threadIdx.x;
    if (tid < 144) w0s[tid] = (float)w0[tid];
#pragma unroll
    for (int i = 0; i < 6; i++) {
        int cid = tid + i * 256;
        int mc  = (cid & 127) * 8;
        int cr  = cid >> 7;
        int r = cr % 3, c = cr / 3;
        int nn = n + r - 1;
        int4 val{};
        if (nn >= 0 && nn < 1024)
            val = *reinterpret_cast<const int4*>(&attn1b[((long long)c * 1024 + nn) * 1024 + mc]);
        *reinterpret_cast<int4*>(&sin_[cr * 1024 + mc]) = val;
    }
    __syncthreads();
    float bns[4], bnb[4];
#pragma unroll
    for (int k = 0; k < 4; k++) {
        float inv = rsqrtf((float)var[k] + 1e-5f);
        bns[k] = (float)gamma[k] * inv;
        bnb[k] = (float)beta[k] - (float)mean[k] * bns[k];
    }
    for (int mi = 0; mi < 4; mi++) {
        int m = tid + mi * 256;
        float acc[4] = {0.f, 0.f, 0.f, 0.f};
#pragma unroll
        for (int c = 0; c < 4; c++)
#pragma unroll
            for (int r = 0; r < 3; r++) {
                const int si = (c * 3 + r) * 1024 + m;
                float v0 = (m > 0)    ? (float)sin_[si - 1] : 0.f;
                float v1 = (float)sin_[si];
                float v2 = (m < 1023) ? (float)sin_[si + 1] : 0.f;
#pragma unroll
                for (int k = 0; k < 4; k++) {
                    const float* wr = &w0s[((k * 4 + c) * 3 + r) * 3];
                    acc[k] += wr[0] * v0 + wr[1] * v1 + wr[2] * v2;
                }
            }
#pragma unroll
        for (int k = 0; k < 4; k++)
            stt[k * 1024 + m] = acc[k] * bns[k] + bnb[k];
    }
    __syncthreads();
    const int wavek = tid >> 6, lane = tid & 63;
    float mx = -1e30f;
    for (int i = 0; i < 16; i++) mx = fmaxf(mx, stt[wavek * 1024 + lane + i * 64]);
    for (int off = 32; off; off >>= 1) mx = fmaxf(mx, __shfl_xor(mx, off));
    float sum = 0.f;
    for (int i = 0; i < 16; i++) sum += __expf(stt[wavek * 1024 + lane + i * 64] - mx);
    for (int off = 32; off; off >>= 1) sum += __shfl_xor(sum, off);
    float rinv = 1.0f / sum;
    bf16* go = g + ((long long)wavek * 1024 + n) * 1024;
    for (int i = 0; i < 16; i++) {
        float t = stt[wavek * 1024 + lane + i * 64];
        go[lane + i * 64] = (bf16)(t * __expf(t - mx) * rinv);
    }
}

// ---------------------------------------------------------------------------
// SINGLE-BATCH conv3x3(4->1): writes bf16 ws copy + final output (flag dtype).
// ---------------------------------------------------------------------------
__global__ __launch_bounds__(256) void k_conv1(
    const bf16* __restrict__ g, const bf16* __restrict__ w1,
    bf16* __restrict__ aws, void* __restrict__ dout, long long foff,
    const int* __restrict__ nf)
{
    __shared__ __align__(16) bf16 sin_[12 * 1024];
    __shared__ float w1s[36];
    const int n = blockIdx.x;
    const int tid = threadIdx.x;
    const bool f32o = (*nf > NANTHRESH);
    if (tid < 36) w1s[tid] = (float)w1[tid];
#pragma unroll
    for (int i = 0; i < 6; i++) {
        int cid = tid + i * 256;
        int mc  = (cid & 127) * 8;
        int cr  = cid >> 7;
        int r = cr % 3, c = cr / 3;
        int nn = n + r - 1;
        int4 val{};
        if (nn >= 0 && nn < 1024)
            val = *reinterpret_cast<const int4*>(&g[((long long)c * 1024 + nn) * 1024 + mc]);
        *reinterpret_cast<int4*>(&sin_[cr * 1024 + mc]) = val;
    }
    __syncthreads();
    for (int mi = 0; mi < 4; mi++) {
        int m = tid + mi * 256;
        float acc = 0.f;
#pragma unroll
        for (int c = 0; c < 4; c++)
#pragma unroll
            for (int r = 0; r < 3; r++) {
                const int si = (c * 3 + r) * 1024 + m;
                float v0 = (m > 0)    ? (float)sin_[si - 1] : 0.f;
                float v1 = (float)sin_[si];
                float v2 = (m < 1023) ? (float)sin_[si + 1] : 0.f;
                const float* wr = &w1s[(c * 3 + r) * 3];
                acc += wr[0] * v0 + wr[1] * v1 + wr[2] * v2;
            }
        aws[(long long)n * 1024 + m] = (bf16)acc;
        long long idx = foff + (long long)n * 1024 + m;
        if (f32o) ((float*)dout)[idx] = acc;
        else      ((bf16*)dout)[idx] = (bf16)acc;
    }
}

// ---------------------------------------------------------------------------
// im2col: src [B][N][C] -> dst [B][N][C*9] (k = ci*9 + t)
// ---------------------------------------------------------------------------
__global__ __launch_bounds__(256) void k_im2col(
    const bf16* __restrict__ src, bf16* __restrict__ dst)
{
    const int blk = blockIdx.x;
    const int b = blk >> 10, n = blk & 1023;
    const int h = n >> 5, w = n & 31;
    const int ci = threadIdx.x;
    const bf16* sb = src + (long long)b * 262144;
    bf16* db = dst + ((long long)b * 1024 + n) * 2304 + ci * 9;
#pragma unroll
    for (int dh = 0; dh < 3; dh++)
#pragma unroll
        for (int dw_ = 0; dw_ < 3; dw_++) {
            int hh = h + dh - 1, ww = w + dw_ - 1;
            bf16 vv = (bf16)0.0f;
            if (hh >= 0 && hh < 32 && ww >= 0 && ww < 32)
                vv = sb[(hh * 32 + ww) * 256 + ci];
            db[dh * 3 + dw_] = vv;
        }
}

extern "C" void kernel_launch(void* const* d_in, const int* in_sizes, int n_in,
                              void* d_out, int out_size, void* d_ws, size_t ws_size,
                              hipStream_t stream)
{
    bf16* ws = (bf16*)d_ws;
    int* flagp = (int*)(ws + FLAG_ELOFF);

    bf16* cw      = ws + CW_OFF;
    bf16* cx      = ws + CX_OFF;
    bf16* dwq     = ws + DWQ_OFF;
    bf16* dwk     = ws + DWK_OFF;
    bf16* dwv     = ws + DWV_OFF;
    bf16* qT      = ws + QT_OFF;
    bf16* kT      = ws + KT_OFF;
    bf16* v       = ws + V_OFF;
    bf16* aws     = ws + AWS_OFF;
    bf16* at1     = ws + AT1_OFF;
    bf16* gb      = ws + GB_OFF;
    bf16* outp    = ws + OUTP_OFF;
    bf16* colbuf  = ws + COL_OFF;

    bf16* c_qa_dw_w = cw + 0;      bf16* c_qa_dw_b = cw + 2304;
    bf16* c_qa_pw_w = cw + 2560;   bf16* c_qa_pw_b = cw + 68096;
    bf16* c_ka_dw_w = cw + 68352;  bf16* c_ka_dw_b = cw + 70656;
    bf16* c_ka_pw_w = cw + 70912;  bf16* c_ka_pw_b = cw + 333056;
    bf16* c_va_dw_w = cw + 334080; bf16* c_va_dw_b = cw + 336384;
    bf16* c_va_pw_w = cw + 336640; bf16* c_va_pw_b = cw + 402176;
    bf16* c_attn0   = cw + 402432;
    bf16* c_bn_g    = cw + 402576; bf16* c_bn_b = cw + 402580;
    bf16* c_bn_m    = cw + 402584; bf16* c_bn_v = cw + 402588;
    bf16* c_attn1   = cw + 402592;
    bf16* c_proj    = cw + 402640;

    // 0) detect input dtype, normalize everything to bf16 ws buffers
    k_zero<<<1, 64, 0, stream>>>(flagp);
    k_detect<<<64, 256, 0, stream>>>((const unsigned short*)d_in[0], flagp);
    SrcPtrs sp;
    for (int i = 0; i < 20; i++) sp.p[i] = d_in[i];
    k_convert<<<dim3(1024, 20), 256, 0, stream>>>(sp, ws, flagp);

    // 1) depthwise convs (transposed outputs)
    k_dw<<<8192, 256, 0, stream>>>(cx, c_qa_dw_w, c_qa_dw_b, c_ka_dw_w, c_ka_dw_b,
                                   c_va_dw_w, c_va_dw_b, dwq, dwk, dwv);
    // 2) pointwise GEMMs
    gemm_nt<<<dim3(4, 128, 1), 256, 0, stream>>>(dwq, c_qa_pw_w, c_qa_pw_b, qT,
        256, 256, 256, 256, 1, 0, 0, 0, 0, 0, 0, 1.0f, 2, flagp, 0);
    gemm_nt<<<dim3(16, 128, 1), 256, 0, stream>>>(dwk, c_ka_pw_w, c_ka_pw_b, kT,
        256, 256, 256, 1024, 1, 0, 0, 0, 0, 0, 0, 1.0f, 2, flagp, 0);
    gemm_nt<<<dim3(128, 4, 1), 256, 0, stream>>>(c_va_pw_w, dwv, c_va_pw_b, v,
        256, 256, 256, 8192, 1, 0, 0, 0, 0, 0, 0, 1.0f, 1, flagp, 0);
    // 3-5) per-batch attention middle
    for (int b = 0; b < 8; b++) {
        gemm_nt<<<dim3(16, 16, 4), 256, 0, stream>>>(
            qT + (long long)b * 262144, kT + (long long)b * 1048576, nullptr, at1,
            256, 256, 1024, 1024,
            1, 0LL, 0LL, 256LL, 0LL, 1048576LL, 0LL, 0.0625f, 0, flagp, 0);
        k_mid<<<1024, 256, 0, stream>>>(at1, c_attn0, c_bn_g, c_bn_b, c_bn_m, c_bn_v, gb);
        k_conv1<<<1024, 256, 0, stream>>>(gb, c_attn1, aws + (long long)b * 1048576,
                                          d_out, 2097152LL + (long long)b * 1048576LL, flagp);
    }
    // 6) outp[b][n][c] = sum_m aws[b][n][m] * v[c][b*1024+m]
    gemm_nt<<<dim3(4, 16, 8), 256, 0, stream>>>(aws, v, nullptr, outp,
        1024, 1024, 8192, 256,
        1, 1048576LL, 0LL, 1024LL, 0LL, 262144LL, 0LL, 1.0f, 0, flagp, 0);
    // 7) proj conv: im2col + GEMM -> out0 (flag dtype)
    k_im2col<<<8192, 256, 0, stream>>>(outp, colbuf);
    gemm_nt<<<dim3(16, 4, 8), 256, 0, stream>>>(c_proj, colbuf, nullptr, d_out,
        2304, 2304, 2304, 1024,
        1, 0LL, 0LL, 2359296LL, 0LL, 262144LL, 0LL, 1.0f, 0, flagp, 1);
}

// Round 4
// 545.115 us; speedup vs baseline: 1.1535x; 1.1535x over previous
//
#include <hip/hip_runtime.h>

using bf16   = __bf16;
using bf16x8 = __bf16 __attribute__((ext_vector_type(8)));
using f32x4  = float  __attribute__((ext_vector_type(4)));

#define NANTHRESH 64

// ---- workspace element offsets (bf16 elements) --------------------------
#define QT_OFF    0LL          // [B*N][C]      2,097,152
#define KT_OFF    2097152LL    // [B*N][4C]     8,388,608
#define V_OFF     10485760LL   // [C][B*N]      2,097,152
#define AWS_OFF   12582912LL   // [B][N][N] attn bf16 copy  8,388,608
#define AT1_OFF   20971520LL   // [4][N][N] per-b           4,194,304
#define GB_OFF    25165824LL   // [4][N][N] per-b           4,194,304
#define CW_OFF    29360128LL   // converted weights          992,464
#define FLAG_ELOFF 30352640LL  // int flag
// phase-A overlays (dead before their hosts are written):
#define CX_OFF    12582912LL   // converted x (alias AWS)
#define DWQ_OFF   14680064LL
#define DWK_OFF   16777216LL
#define DWV_OFF   18874368LL
// phase-C overlays:
#define OUTP_OFF  20971520LL   // stage-6 out [B][N][C] (alias AT1)
#define COL_OFF   0LL          // im2col [B][N][2304] (alias QT/KT/V/AWS, all dead)

__device__ __constant__ int g_nsz[20] = {
    2097152, 2304,256,65536,256, 2304,256,262144,1024,
    2304,256,65536,256, 144, 4,4,4,4, 36, 589824};
__device__ __constant__ long long g_doff[20] = {
    CX_OFF,
    CW_OFF+0,      CW_OFF+2304,   CW_OFF+2560,   CW_OFF+68096,
    CW_OFF+68352,  CW_OFF+70656,  CW_OFF+70912,  CW_OFF+333056,
    CW_OFF+334080, CW_OFF+336384, CW_OFF+336640, CW_OFF+402176,
    CW_OFF+402432, CW_OFF+402576, CW_OFF+402580, CW_OFF+402584,
    CW_OFF+402588, CW_OFF+402592, CW_OFF+402640};

struct SrcPtrs { const void* p[20]; };

__global__ void k_zero(int* p) { if (threadIdx.x < 4) p[threadIdx.x] = 0; }

// Count inf/NaN bit patterns among the first 262,144 16-bit halves of x.
// fp32 data -> low halves have random exponent field -> ~512 hits; bf16 -> 0.
__global__ __launch_bounds__(256) void k_detect(const unsigned short* __restrict__ xs,
                                                int* __restrict__ cnt)
{
    int idx = blockIdx.x * 256 + threadIdx.x;
    int c = 0;
#pragma unroll
    for (int i = 0; i < 16; i++) {
        unsigned short h = xs[idx + i * 16384];
        c += ((h & 0x7F80) == 0x7F80);
    }
    if (c) atomicAdd(cnt, c);
}

// Normalize every input tensor into a bf16 ws buffer (branch on detect flag).
__global__ __launch_bounds__(256) void k_convert(SrcPtrs sp, bf16* __restrict__ wsb,
                                                 const int* __restrict__ nf)
{
    const int t = blockIdx.y;
    const int n = g_nsz[t];
    const bool srcf32 = (*nf > NANTHRESH);
    const void* src = sp.p[t];
    bf16* dst = wsb + g_doff[t];
    for (int i = blockIdx.x * 256 + threadIdx.x; i < n; i += 256 * 256) {
        float f = srcf32 ? ((const float*)src)[i] : (float)((const bf16*)src)[i];
        if (!(fabsf(f) < 1e30f)) f = 0.f;
        dst[i] = (bf16)f;
    }
}

// ---------------------------------------------------------------------------
// Canonical NT MFMA GEMM: D[M][N] = alpha*A[M][K]@B[K][N] (+bias).
// ---------------------------------------------------------------------------
__global__ __launch_bounds__(256) void gemm_nt(
    const bf16* __restrict__ A, const bf16* __restrict__ Bc,
    const bf16* __restrict__ bias, void* __restrict__ Dv,
    int K, int lda, int ldb, int ldd,
    int zdiv, long long sA1, long long sA2, long long sB1, long long sB2,
    long long sD1, long long sD2, float alpha, int bias_mode,
    const int* __restrict__ nf, int dyn)
{
    const int z  = blockIdx.z;
    const int zq = z / zdiv, zr = z % zdiv;
    A  += (long long)zq * sA1 + (long long)zr * sA2;
    Bc += (long long)zq * sB1 + (long long)zr * sB2;
    const long long zoff = (long long)zq * sD1 + (long long)zr * sD2;
    const bool f32o = dyn && (*nf > NANTHRESH);
    const int m0 = blockIdx.y * 64;
    const int n0 = blockIdx.x * 64;
    __shared__ __align__(16) bf16 As[64 * 72];
    __shared__ __align__(16) bf16 Bs[64 * 72];
    const int tid  = threadIdx.x;
    const int lane = tid & 63;
    const int wave = tid >> 6;
    const int wm   = (wave >> 1) * 32;
    const int wn   = (wave & 1) * 32;
    const int quad = lane >> 4;
    const int l16  = lane & 15;
    f32x4 acc[2][2] = {};
    for (int k0 = 0; k0 < K; k0 += 64) {
#pragma unroll
        for (int i = 0; i < 2; i++) {
            int cid = tid + i * 256;
            int row = cid >> 3;
            int kc  = (cid & 7) * 8;
            *reinterpret_cast<int4*>(&As[row * 72 + kc]) =
                *reinterpret_cast<const int4*>(&A[(long long)(m0 + row) * lda + k0 + kc]);
            *reinterpret_cast<int4*>(&Bs[row * 72 + kc]) =
                *reinterpret_cast<const int4*>(&Bc[(long long)(n0 + row) * ldb + k0 + kc]);
        }
        __syncthreads();
#pragma unroll
        for (int ks = 0; ks < 2; ks++) {
            bf16x8 af[2], bfr[2];
#pragma unroll
            for (int i = 0; i < 2; i++) {
                af[i]  = *reinterpret_cast<const bf16x8*>(&As[(wm + i * 16 + l16) * 72 + ks * 32 + quad * 8]);
                bfr[i] = *reinterpret_cast<const bf16x8*>(&Bs[(wn + i * 16 + l16) * 72 + ks * 32 + quad * 8]);
            }
#pragma unroll
            for (int i = 0; i < 2; i++)
#pragma unroll
                for (int j = 0; j < 2; j++)
                    acc[i][j] = __builtin_amdgcn_mfma_f32_16x16x32_bf16(af[i], bfr[j], acc[i][j], 0, 0, 0);
        }
        __syncthreads();
    }
#pragma unroll
    for (int i = 0; i < 2; i++)
#pragma unroll
        for (int j = 0; j < 2; j++)
#pragma unroll
            for (int r = 0; r < 4; r++) {
                int row = m0 + wm + i * 16 + quad * 4 + r;
                int col = n0 + wn + j * 16 + l16;
                float v = acc[i][j][r] * alpha;
                if (bias_mode == 1) v += (float)bias[row];
                else if (bias_mode == 2) v += (float)bias[col];
                long long idx = zoff + (long long)row * ldd + col;
                if (f32o) ((float*)Dv)[idx] = v;
                else      ((bf16*)Dv)[idx] = (bf16)v;
            }
}

// ---------------------------------------------------------------------------
// Depthwise 3x3 (SAME) q/k/v fused, COALESCED rewrite.
// grid (ct=4, hp=16, b=8); block 256. Thread: channel c=t&63, wave quadrant
// psub=t>>6 -> output row h0+(psub>>1), w-half (psub&1)*16.
// Loads: 3 halo rows x 16px as aligned int4 (row = one 64B line, L1-shared).
// Outputs transposed [b][n][c] via LDS tile, 128B-contiguous int4 stores.
// ---------------------------------------------------------------------------
__global__ __launch_bounds__(256) void k_dw(
    const bf16* __restrict__ x,
    const bf16* __restrict__ wq, const bf16* __restrict__ bq,
    const bf16* __restrict__ wk, const bf16* __restrict__ bk,
    const bf16* __restrict__ wv, const bf16* __restrict__ bv,
    bf16* __restrict__ dq, bf16* __restrict__ dk, bf16* __restrict__ dv)
{
    __shared__ __align__(16) bf16 obuf[3 * 64 * 72];   // [t3][p][72] 27.6 KB
    const int ct = blockIdx.x, hp = blockIdx.y, b = blockIdx.z;
    const int c0 = ct * 64, h0 = hp * 2, n0 = hp * 64;
    const int t = threadIdx.x;
    const int c = t & 63, psub = t >> 6;
    const int hl = psub >> 1, wbase = (psub & 1) * 16;
    const int gc = c0 + c;
    const int h = h0 + hl;

    // --- load 3 halo rows (18 floats each: [left | 16 px | right]) ---
    float xr[3][18];
    const bf16* chbase = x + ((long long)b * 256 + gc) * 1024;
#pragma unroll
    for (int r = 0; r < 3; r++) {
        int hr = h + r - 1;
        if (hr >= 0 && hr < 32) {
            const bf16* rp = chbase + hr * 32;
            bf16x8 v0 = *reinterpret_cast<const bf16x8*>(rp + wbase);
            bf16x8 v1 = *reinterpret_cast<const bf16x8*>(rp + wbase + 8);
#pragma unroll
            for (int j = 0; j < 8; j++) { xr[r][1 + j] = (float)v0[j]; xr[r][9 + j] = (float)v1[j]; }
            xr[r][0]  = (wbase > 0)       ? (float)rp[wbase - 1]  : 0.f;
            xr[r][17] = (wbase + 16 < 32) ? (float)rp[wbase + 16] : 0.f;
        } else {
#pragma unroll
            for (int j = 0; j < 18; j++) xr[r][j] = 0.f;
        }
    }
    // --- weights/bias (tiny, L1-cached) ---
    float wrq[9], wrk[9], wrv[9];
#pragma unroll
    for (int j = 0; j < 9; j++) {
        wrq[j] = (float)wq[gc * 9 + j];
        wrk[j] = (float)wk[gc * 9 + j];
        wrv[j] = (float)wv[gc * 9 + j];
    }
    const float biq = (float)bq[gc], bik = (float)bk[gc], biv = (float)bv[gc];

    // --- compute 16 outputs, stage transposed in LDS ---
#pragma unroll
    for (int i = 0; i < 16; i++) {
        float aq = biq, ak = bik, av = biv;
#pragma unroll
        for (int r = 0; r < 3; r++)
#pragma unroll
            for (int d = 0; d < 3; d++) {
                float xv = xr[r][i + d];
                aq += xv * wrq[r * 3 + d];
                ak += xv * wrk[r * 3 + d];
                av += xv * wrv[r * 3 + d];
            }
        int p = hl * 32 + wbase + i;
        obuf[0 * 4608 + p * 72 + c] = (bf16)aq;
        obuf[1 * 4608 + p * 72 + c] = (bf16)ak;
        obuf[2 * 4608 + p * 72 + c] = (bf16)av;
    }
    __syncthreads();

    // --- transposed stores: [b][n0+p][c0 + chunk*8] int4 runs ---
    bf16* dsts[3] = {dq, dk, dv};
    const int chunk = t & 7, pr0 = t >> 3;
#pragma unroll
    for (int t3 = 0; t3 < 3; t3++) {
        bf16* dst = dsts[t3];
#pragma unroll
        for (int rep = 0; rep < 2; rep++) {
            int pr = pr0 + rep * 32;
            int4 val = *reinterpret_cast<const int4*>(&obuf[t3 * 4608 + pr * 72 + chunk * 8]);
            *reinterpret_cast<int4*>(&dst[((long long)b * 1024 + n0 + pr) * 256 + c0 + chunk * 8]) = val;
        }
    }
}

// ---------------------------------------------------------------------------
// SINGLE-BATCH conv3x3(4->4)+BN+self-gating x*softmax(x, m-axis).
// ---------------------------------------------------------------------------
__global__ __launch_bounds__(256) void k_mid(
    const bf16* __restrict__ attn1b, const bf16* __restrict__ w0,
    const bf16* __restrict__ gamma, const bf16* __restrict__ beta,
    const bf16* __restrict__ mean,  const bf16* __restrict__ var,
    bf16* __restrict__ g)
{
    __shared__ __align__(16) bf16 sin_[12 * 1024];
    __shared__ float stt[4 * 1024];
    __shared__ float w0s[144];
    const int n = blockIdx.x;
    const int tid = threadIdx.x;
    if (tid < 144) w0s[tid] = (float)w0[tid];
#pragma unroll
    for (int i = 0; i < 6; i++) {
        int cid = tid + i * 256;
        int mc  = (cid & 127) * 8;
        int cr  = cid >> 7;
        int r = cr % 3, c = cr / 3;
        int nn = n + r - 1;
        int4 val{};
        if (nn >= 0 && nn < 1024)
            val = *reinterpret_cast<const int4*>(&attn1b[((long long)c * 1024 + nn) * 1024 + mc]);
        *reinterpret_cast<int4*>(&sin_[cr * 1024 + mc]) = val;
    }
    __syncthreads();
    float bns[4], bnb[4];
#pragma unroll
    for (int k = 0; k < 4; k++) {
        float inv = rsqrtf((float)var[k] + 1e-5f);
        bns[k] = (float)gamma[k] * inv;
        bnb[k] = (float)beta[k] - (float)mean[k] * bns[k];
    }
    for (int mi = 0; mi < 4; mi++) {
        int m = tid + mi * 256;
        float acc[4] = {0.f, 0.f, 0.f, 0.f};
#pragma unroll
        for (int c = 0; c < 4; c++)
#pragma unroll
            for (int r = 0; r < 3; r++) {
                const int si = (c * 3 + r) * 1024 + m;
                float v0 = (m > 0)    ? (float)sin_[si - 1] : 0.f;
                float v1 = (float)sin_[si];
                float v2 = (m < 1023) ? (float)sin_[si + 1] : 0.f;
#pragma unroll
                for (int k = 0; k < 4; k++) {
                    const float* wr = &w0s[((k * 4 + c) * 3 + r) * 3];
                    acc[k] += wr[0] * v0 + wr[1] * v1 + wr[2] * v2;
                }
            }
#pragma unroll
        for (int k = 0; k < 4; k++)
            stt[k * 1024 + m] = acc[k] * bns[k] + bnb[k];
    }
    __syncthreads();
    const int wavek = tid >> 6, lane = tid & 63;
    float mx = -1e30f;
    for (int i = 0; i < 16; i++) mx = fmaxf(mx, stt[wavek * 1024 + lane + i * 64]);
    for (int off = 32; off; off >>= 1) mx = fmaxf(mx, __shfl_xor(mx, off));
    float sum = 0.f;
    for (int i = 0; i < 16; i++) sum += __expf(stt[wavek * 1024 + lane + i * 64] - mx);
    for (int off = 32; off; off >>= 1) sum += __shfl_xor(sum, off);
    float rinv = 1.0f / sum;
    bf16* go = g + ((long long)wavek * 1024 + n) * 1024;
    for (int i = 0; i < 16; i++) {
        float t = stt[wavek * 1024 + lane + i * 64];
        go[lane + i * 64] = (bf16)(t * __expf(t - mx) * rinv);
    }
}

// ---------------------------------------------------------------------------
// SINGLE-BATCH conv3x3(4->1): writes bf16 ws copy + final output (flag dtype).
// ---------------------------------------------------------------------------
__global__ __launch_bounds__(256) void k_conv1(
    const bf16* __restrict__ g, const bf16* __restrict__ w1,
    bf16* __restrict__ aws, void* __restrict__ dout, long long foff,
    const int* __restrict__ nf)
{
    __shared__ __align__(16) bf16 sin_[12 * 1024];
    __shared__ float w1s[36];
    const int n = blockIdx.x;
    const int tid = threadIdx.x;
    const bool f32o = (*nf > NANTHRESH);
    if (tid < 36) w1s[tid] = (float)w1[tid];
#pragma unroll
    for (int i = 0; i < 6; i++) {
        int cid = tid + i * 256;
        int mc  = (cid & 127) * 8;
        int cr  = cid >> 7;
        int r = cr % 3, c = cr / 3;
        int nn = n + r - 1;
        int4 val{};
        if (nn >= 0 && nn < 1024)
            val = *reinterpret_cast<const int4*>(&g[((long long)c * 1024 + nn) * 1024 + mc]);
        *reinterpret_cast<int4*>(&sin_[cr * 1024 + mc]) = val;
    }
    __syncthreads();
    for (int mi = 0; mi < 4; mi++) {
        int m = tid + mi * 256;
        float acc = 0.f;
#pragma unroll
        for (int c = 0; c < 4; c++)
#pragma unroll
            for (int r = 0; r < 3; r++) {
                const int si = (c * 3 + r) * 1024 + m;
                float v0 = (m > 0)    ? (float)sin_[si - 1] : 0.f;
                float v1 = (float)sin_[si];
                float v2 = (m < 1023) ? (float)sin_[si + 1] : 0.f;
                const float* wr = &w1s[(c * 3 + r) * 3];
                acc += wr[0] * v0 + wr[1] * v1 + wr[2] * v2;
            }
        aws[(long long)n * 1024 + m] = (bf16)acc;
        long long idx = foff + (long long)n * 1024 + m;
        if (f32o) ((float*)dout)[idx] = acc;
        else      ((bf16*)dout)[idx] = (bf16)acc;
    }
}

// ---------------------------------------------------------------------------
// im2col: src [B][N][C] -> dst [B][N][C*9] (k = ci*9 + t)
// ---------------------------------------------------------------------------
__global__ __launch_bounds__(256) void k_im2col(
    const bf16* __restrict__ src, bf16* __restrict__ dst)
{
    const int blk = blockIdx.x;
    const int b = blk >> 10, n = blk & 1023;
    const int h = n >> 5, w = n & 31;
    const int ci = threadIdx.x;
    const bf16* sb = src + (long long)b * 262144;
    bf16* db = dst + ((long long)b * 1024 + n) * 2304 + ci * 9;
#pragma unroll
    for (int dh = 0; dh < 3; dh++)
#pragma unroll
        for (int dw_ = 0; dw_ < 3; dw_++) {
            int hh = h + dh - 1, ww = w + dw_ - 1;
            bf16 vv = (bf16)0.0f;
            if (hh >= 0 && hh < 32 && ww >= 0 && ww < 32)
                vv = sb[(hh * 32 + ww) * 256 + ci];
            db[dh * 3 + dw_] = vv;
        }
}

extern "C" void kernel_launch(void* const* d_in, const int* in_sizes, int n_in,
                              void* d_out, int out_size, void* d_ws, size_t ws_size,
                              hipStream_t stream)
{
    bf16* ws = (bf16*)d_ws;
    int* flagp = (int*)(ws + FLAG_ELOFF);

    bf16* cw      = ws + CW_OFF;
    bf16* cx      = ws + CX_OFF;
    bf16* dwq     = ws + DWQ_OFF;
    bf16* dwk     = ws + DWK_OFF;
    bf16* dwv     = ws + DWV_OFF;
    bf16* qT      = ws + QT_OFF;
    bf16* kT      = ws + KT_OFF;
    bf16* v       = ws + V_OFF;
    bf16* aws     = ws + AWS_OFF;
    bf16* at1     = ws + AT1_OFF;
    bf16* gb      = ws + GB_OFF;
    bf16* outp    = ws + OUTP_OFF;
    bf16* colbuf  = ws + COL_OFF;

    bf16* c_qa_dw_w = cw + 0;      bf16* c_qa_dw_b = cw + 2304;
    bf16* c_qa_pw_w = cw + 2560;   bf16* c_qa_pw_b = cw + 68096;
    bf16* c_ka_dw_w = cw + 68352;  bf16* c_ka_dw_b = cw + 70656;
    bf16* c_ka_pw_w = cw + 70912;  bf16* c_ka_pw_b = cw + 333056;
    bf16* c_va_dw_w = cw + 334080; bf16* c_va_dw_b = cw + 336384;
    bf16* c_va_pw_w = cw + 336640; bf16* c_va_pw_b = cw + 402176;
    bf16* c_attn0   = cw + 402432;
    bf16* c_bn_g    = cw + 402576; bf16* c_bn_b = cw + 402580;
    bf16* c_bn_m    = cw + 402584; bf16* c_bn_v = cw + 402588;
    bf16* c_attn1   = cw + 402592;
    bf16* c_proj    = cw + 402640;

    // 0) detect input dtype, normalize everything to bf16 ws buffers
    k_zero<<<1, 64, 0, stream>>>(flagp);
    k_detect<<<64, 256, 0, stream>>>((const unsigned short*)d_in[0], flagp);
    SrcPtrs sp;
    for (int i = 0; i < 20; i++) sp.p[i] = d_in[i];
    k_convert<<<dim3(256, 20), 256, 0, stream>>>(sp, ws, flagp);

    // 1) depthwise convs (transposed outputs), coalesced rewrite
    k_dw<<<dim3(4, 16, 8), 256, 0, stream>>>(cx, c_qa_dw_w, c_qa_dw_b, c_ka_dw_w, c_ka_dw_b,
                                             c_va_dw_w, c_va_dw_b, dwq, dwk, dwv);
    // 2) pointwise GEMMs
    gemm_nt<<<dim3(4, 128, 1), 256, 0, stream>>>(dwq, c_qa_pw_w, c_qa_pw_b, qT,
        256, 256, 256, 256, 1, 0, 0, 0, 0, 0, 0, 1.0f, 2, flagp, 0);
    gemm_nt<<<dim3(16, 128, 1), 256, 0, stream>>>(dwk, c_ka_pw_w, c_ka_pw_b, kT,
        256, 256, 256, 1024, 1, 0, 0, 0, 0, 0, 0, 1.0f, 2, flagp, 0);
    gemm_nt<<<dim3(128, 4, 1), 256, 0, stream>>>(c_va_pw_w, dwv, c_va_pw_b, v,
        256, 256, 256, 8192, 1, 0, 0, 0, 0, 0, 0, 1.0f, 1, flagp, 0);
    // 3-5) per-batch attention middle
    for (int b = 0; b < 8; b++) {
        gemm_nt<<<dim3(16, 16, 4), 256, 0, stream>>>(
            qT + (long long)b * 262144, kT + (long long)b * 1048576, nullptr, at1,
            256, 256, 1024, 1024,
            1, 0LL, 0LL, 256LL, 0LL, 1048576LL, 0LL, 0.0625f, 0, flagp, 0);
        k_mid<<<1024, 256, 0, stream>>>(at1, c_attn0, c_bn_g, c_bn_b, c_bn_m, c_bn_v, gb);
        k_conv1<<<1024, 256, 0, stream>>>(gb, c_attn1, aws + (long long)b * 1048576,
                                          d_out, 2097152LL + (long long)b * 1048576LL, flagp);
    }
    // 6) outp[b][n][c] = sum_m aws[b][n][m] * v[c][b*1024+m]
    gemm_nt<<<dim3(4, 16, 8), 256, 0, stream>>>(aws, v, nullptr, outp,
        1024, 1024, 8192, 256,
        1, 1048576LL, 0LL, 1024LL, 0LL, 262144LL, 0LL, 1.0f, 0, flagp, 0);
    // 7) proj conv: im2col + GEMM -> out0 (flag dtype)
    k_im2col<<<8192, 256, 0, stream>>>(outp, colbuf);
    gemm_nt<<<dim3(16, 4, 8), 256, 0, stream>>>(c_proj, colbuf, nullptr, d_out,
        2304, 2304, 2304, 1024,
        1, 0LL, 0LL, 2359296LL, 0LL, 262144LL, 0LL, 1.0f, 0, flagp, 1);
}

// Round 5
// 404.999 us; speedup vs baseline: 1.5526x; 1.3460x over previous
//
#include <hip/hip_runtime.h>

using bf16   = __bf16;
using bf16x4 = __bf16 __attribute__((ext_vector_type(4)));
using bf16x8 = __bf16 __attribute__((ext_vector_type(8)));
using f32x4  = float  __attribute__((ext_vector_type(4)));

#define NANTHRESH 64

// ---- workspace element offsets (bf16 elements) --------------------------
#define QT_OFF    0LL          // [B*N][C]      2,097,152
#define KT_OFF    2097152LL    // [B*N][4C]     8,388,608
#define V_OFF     10485760LL   // [C][B*N]      2,097,152
#define AWS_OFF   12582912LL   // [B][N][N] attn bf16 copy  8,388,608
#define ATT_OFF   20971520LL   // [B][4][N][N]  33,554,432
#define CW_OFF    54525952LL   // converted weights 992,464
#define FLAG_ELOFF 55518416LL  // int flag
// overlays:
#define CX_OFF    20971520LL   // converted x (ATT region, dead before attn GEMM)
#define DWQ_OFF   23068672LL
#define DWK_OFF   25165824LL
#define DWV_OFF   27262976LL
#define OUTP_OFF  20971520LL   // stage-6 out [B][N][C] (ATT dead after k_midconv)
#define COL_OFF   0LL          // im2col [B][N][2304] (QT..AWS dead after stage6)

__device__ __constant__ int g_nsz[20] = {
    2097152, 2304,256,65536,256, 2304,256,262144,1024,
    2304,256,65536,256, 144, 4,4,4,4, 36, 589824};
__device__ __constant__ long long g_doff[20] = {
    CX_OFF,
    CW_OFF+0,      CW_OFF+2304,   CW_OFF+2560,   CW_OFF+68096,
    CW_OFF+68352,  CW_OFF+70656,  CW_OFF+70912,  CW_OFF+333056,
    CW_OFF+334080, CW_OFF+336384, CW_OFF+336640, CW_OFF+402176,
    CW_OFF+402432, CW_OFF+402576, CW_OFF+402580, CW_OFF+402584,
    CW_OFF+402588, CW_OFF+402592, CW_OFF+402640};

struct SrcPtrs { const void* p[20]; };

__global__ void k_zero(int* p) { if (threadIdx.x < 4) p[threadIdx.x] = 0; }

// fp32 data read as 16-bit halves -> random exponent field -> ~512 hits; bf16 -> 0.
__global__ __launch_bounds__(256) void k_detect(const unsigned short* __restrict__ xs,
                                                int* __restrict__ cnt)
{
    int idx = blockIdx.x * 256 + threadIdx.x;
    int c = 0;
#pragma unroll
    for (int i = 0; i < 16; i++) {
        unsigned short h = xs[idx + i * 16384];
        c += ((h & 0x7F80) == 0x7F80);
    }
    if (c) atomicAdd(cnt, c);
}

__global__ __launch_bounds__(256) void k_convert(SrcPtrs sp, bf16* __restrict__ wsb,
                                                 const int* __restrict__ nf)
{
    const int t = blockIdx.y;
    const int n = g_nsz[t];
    const bool srcf32 = (*nf > NANTHRESH);
    const void* src = sp.p[t];
    bf16* dst = wsb + g_doff[t];
    for (int i = blockIdx.x * 256 + threadIdx.x; i < n; i += 256 * 256) {
        float f = srcf32 ? ((const float*)src)[i] : (float)((const bf16*)src)[i];
        if (!(fabsf(f) < 1e30f)) f = 0.f;
        dst[i] = (bf16)f;
    }
}

// ---------------------------------------------------------------------------
// Canonical NT MFMA GEMM (64x64 tile, BK=64, 16x16x32 bf16 MFMA)
// ---------------------------------------------------------------------------
__global__ __launch_bounds__(256) void gemm_nt(
    const bf16* __restrict__ A, const bf16* __restrict__ Bc,
    const bf16* __restrict__ bias, void* __restrict__ Dv,
    int K, int lda, int ldb, int ldd,
    int zdiv, long long sA1, long long sA2, long long sB1, long long sB2,
    long long sD1, long long sD2, float alpha, int bias_mode,
    const int* __restrict__ nf, int dyn)
{
    const int z  = blockIdx.z;
    const int zq = z / zdiv, zr = z % zdiv;
    A  += (long long)zq * sA1 + (long long)zr * sA2;
    Bc += (long long)zq * sB1 + (long long)zr * sB2;
    const long long zoff = (long long)zq * sD1 + (long long)zr * sD2;
    const bool f32o = dyn && (*nf > NANTHRESH);
    const int m0 = blockIdx.y * 64;
    const int n0 = blockIdx.x * 64;
    __shared__ __align__(16) bf16 As[64 * 72];
    __shared__ __align__(16) bf16 Bs[64 * 72];
    const int tid  = threadIdx.x;
    const int lane = tid & 63;
    const int wave = tid >> 6;
    const int wm   = (wave >> 1) * 32;
    const int wn   = (wave & 1) * 32;
    const int quad = lane >> 4;
    const int l16  = lane & 15;
    f32x4 acc[2][2] = {};
    for (int k0 = 0; k0 < K; k0 += 64) {
#pragma unroll
        for (int i = 0; i < 2; i++) {
            int cid = tid + i * 256;
            int row = cid >> 3;
            int kc  = (cid & 7) * 8;
            *reinterpret_cast<int4*>(&As[row * 72 + kc]) =
                *reinterpret_cast<const int4*>(&A[(long long)(m0 + row) * lda + k0 + kc]);
            *reinterpret_cast<int4*>(&Bs[row * 72 + kc]) =
                *reinterpret_cast<const int4*>(&Bc[(long long)(n0 + row) * ldb + k0 + kc]);
        }
        __syncthreads();
#pragma unroll
        for (int ks = 0; ks < 2; ks++) {
            bf16x8 af[2], bfr[2];
#pragma unroll
            for (int i = 0; i < 2; i++) {
                af[i]  = *reinterpret_cast<const bf16x8*>(&As[(wm + i * 16 + l16) * 72 + ks * 32 + quad * 8]);
                bfr[i] = *reinterpret_cast<const bf16x8*>(&Bs[(wn + i * 16 + l16) * 72 + ks * 32 + quad * 8]);
            }
#pragma unroll
            for (int i = 0; i < 2; i++)
#pragma unroll
                for (int j = 0; j < 2; j++)
                    acc[i][j] = __builtin_amdgcn_mfma_f32_16x16x32_bf16(af[i], bfr[j], acc[i][j], 0, 0, 0);
        }
        __syncthreads();
    }
#pragma unroll
    for (int i = 0; i < 2; i++)
#pragma unroll
        for (int j = 0; j < 2; j++)
#pragma unroll
            for (int r = 0; r < 4; r++) {
                int row = m0 + wm + i * 16 + quad * 4 + r;
                int col = n0 + wn + j * 16 + l16;
                float v = acc[i][j][r] * alpha;
                if (bias_mode == 1) v += (float)bias[row];
                else if (bias_mode == 2) v += (float)bias[col];
                long long idx = zoff + (long long)row * ldd + col;
                if (f32o) ((float*)Dv)[idx] = v;
                else      ((bf16*)Dv)[idx] = (bf16)v;
            }
}

// ---------------------------------------------------------------------------
// Depthwise 3x3 q/k/v fused, coalesced (unchanged from round 4)
// ---------------------------------------------------------------------------
__global__ __launch_bounds__(256) void k_dw(
    const bf16* __restrict__ x,
    const bf16* __restrict__ wq, const bf16* __restrict__ bq,
    const bf16* __restrict__ wk, const bf16* __restrict__ bk,
    const bf16* __restrict__ wv, const bf16* __restrict__ bv,
    bf16* __restrict__ dq, bf16* __restrict__ dk, bf16* __restrict__ dv)
{
    __shared__ __align__(16) bf16 obuf[3 * 64 * 72];
    const int ct = blockIdx.x, hp = blockIdx.y, b = blockIdx.z;
    const int c0 = ct * 64, h0 = hp * 2, n0 = hp * 64;
    const int t = threadIdx.x;
    const int c = t & 63, psub = t >> 6;
    const int hl = psub >> 1, wbase = (psub & 1) * 16;
    const int gc = c0 + c;
    const int h = h0 + hl;
    float xr[3][18];
    const bf16* chbase = x + ((long long)b * 256 + gc) * 1024;
#pragma unroll
    for (int r = 0; r < 3; r++) {
        int hr = h + r - 1;
        if (hr >= 0 && hr < 32) {
            const bf16* rp = chbase + hr * 32;
            bf16x8 v0 = *reinterpret_cast<const bf16x8*>(rp + wbase);
            bf16x8 v1 = *reinterpret_cast<const bf16x8*>(rp + wbase + 8);
#pragma unroll
            for (int j = 0; j < 8; j++) { xr[r][1 + j] = (float)v0[j]; xr[r][9 + j] = (float)v1[j]; }
            xr[r][0]  = (wbase > 0)       ? (float)rp[wbase - 1]  : 0.f;
            xr[r][17] = (wbase + 16 < 32) ? (float)rp[wbase + 16] : 0.f;
        } else {
#pragma unroll
            for (int j = 0; j < 18; j++) xr[r][j] = 0.f;
        }
    }
    float wrq[9], wrk[9], wrv[9];
#pragma unroll
    for (int j = 0; j < 9; j++) {
        wrq[j] = (float)wq[gc * 9 + j];
        wrk[j] = (float)wk[gc * 9 + j];
        wrv[j] = (float)wv[gc * 9 + j];
    }
    const float biq = (float)bq[gc], bik = (float)bk[gc], biv = (float)bv[gc];
#pragma unroll
    for (int i = 0; i < 16; i++) {
        float aq = biq, ak = bik, av = biv;
#pragma unroll
        for (int r = 0; r < 3; r++)
#pragma unroll
            for (int d = 0; d < 3; d++) {
                float xv = xr[r][i + d];
                aq += xv * wrq[r * 3 + d];
                ak += xv * wrk[r * 3 + d];
                av += xv * wrv[r * 3 + d];
            }
        int p = hl * 32 + wbase + i;
        obuf[0 * 4608 + p * 72 + c] = (bf16)aq;
        obuf[1 * 4608 + p * 72 + c] = (bf16)ak;
        obuf[2 * 4608 + p * 72 + c] = (bf16)av;
    }
    __syncthreads();
    bf16* dsts[3] = {dq, dk, dv};
    const int chunk = t & 7, pr0 = t >> 3;
#pragma unroll
    for (int t3 = 0; t3 < 3; t3++) {
        bf16* dst = dsts[t3];
#pragma unroll
        for (int rep = 0; rep < 2; rep++) {
            int pr = pr0 + rep * 32;
            int4 val = *reinterpret_cast<const int4*>(&obuf[t3 * 4608 + pr * 72 + chunk * 8]);
            *reinterpret_cast<int4*>(&dst[((long long)b * 1024 + n0 + pr) * 256 + c0 + chunk * 8]) = val;
        }
    }
}

// ---------------------------------------------------------------------------
// FUSED middle: conv3x3(4->4)+BN -> x*softmax(x) -> conv3x3(4->1).
// Tile = 4 output rows (n0..n0+3), one block per (rt, b). Mid rows n0-1..n0+4
// computed in registers (fp32), softmax via bf16 partial scratch, gated rows
// staged bf16 in LDS for the conv1 halo. No gbuf round-trip.
// ---------------------------------------------------------------------------
__global__ __launch_bounds__(256) void k_midconv(
    const bf16* __restrict__ att,   // [B][4][N][N]
    const bf16* __restrict__ w0,
    const bf16* __restrict__ gamma, const bf16* __restrict__ beta,
    const bf16* __restrict__ mean,  const bf16* __restrict__ var,
    const bf16* __restrict__ w1,
    bf16* __restrict__ aws,         // [B][N][N]
    void* __restrict__ dout, const int* __restrict__ nf)
{
    __shared__ __align__(16) bf16 sG[24 * 1024];   // gated mid rows [k][j][m] 48KB
    __shared__ __align__(16) bf16 pm[24 * 256];    // reduction partials 12KB
    __shared__ float w0ld[144];                    // [c][r][k*3+d]
    __shared__ float w1s[36];
    __shared__ float mxs[24], rsum[24];

    const int rt = blockIdx.x, b = blockIdx.y;
    const int n0 = rt * 4;
    const int tid = threadIdx.x;
    const int m0 = tid * 4;
    const int wv_ = tid >> 6, lane = tid & 63;

    if (tid < 144) {
        int c = tid / 36, rem = tid % 36, r = rem / 12, kd = rem % 12;
        int k = kd / 3, d = kd % 3;
        w0ld[(c * 3 + r) * 12 + kd] = (float)w0[((k * 4 + c) * 3 + r) * 3 + d];
    } else if (tid < 180) {
        w1s[tid - 144] = (float)w1[tid - 144];
    }
    float bns[4], bnb[4];
#pragma unroll
    for (int k = 0; k < 4; k++) {
        float inv = rsqrtf((float)var[k] + 1e-5f);
        bns[k] = (float)gamma[k] * inv;
        bnb[k] = (float)beta[k] - (float)mean[k] * bns[k];
    }
    __syncthreads();

    // ---- mid conv: vals[j][k][u], m = m0+u ----
    float vals[6][4][4] = {};
    const bf16* attb = att + (long long)b * 4194304;
    for (int c = 0; c < 4; c++) {
        float rv[8][6];
#pragma unroll
        for (int rw = 0; rw < 8; rw++) {
            int row = n0 - 2 + rw;
            if (row >= 0 && row < 1024) {
                const bf16* rp = attb + ((long long)c * 1024 + row) * 1024;
                bf16x4 t4 = *reinterpret_cast<const bf16x4*>(rp + m0);
#pragma unroll
                for (int u = 0; u < 4; u++) rv[rw][1 + u] = (float)t4[u];
                rv[rw][0] = (m0 > 0)        ? (float)rp[m0 - 1] : 0.f;
                rv[rw][5] = (m0 + 4 < 1024) ? (float)rp[m0 + 4] : 0.f;
            } else {
#pragma unroll
                for (int u = 0; u < 6; u++) rv[rw][u] = 0.f;
            }
        }
#pragma unroll
        for (int r = 0; r < 3; r++) {
            float wvv[12];
#pragma unroll
            for (int q = 0; q < 12; q++) wvv[q] = w0ld[(c * 3 + r) * 12 + q];
#pragma unroll
            for (int j = 0; j < 6; j++)
#pragma unroll
                for (int k = 0; k < 4; k++)
#pragma unroll
                    for (int d = 0; d < 3; d++)
#pragma unroll
                        for (int u = 0; u < 4; u++)
                            vals[j][k][u] += wvv[k * 3 + d] * rv[j + r][u + d];
        }
    }
    // BN
#pragma unroll
    for (int j = 0; j < 6; j++)
#pragma unroll
        for (int k = 0; k < 4; k++)
#pragma unroll
            for (int u = 0; u < 4; u++)
                vals[j][k][u] = vals[j][k][u] * bns[k] + bnb[k];

    // ---- softmax over m per (k,j) row: rid = k*6+j ----
#pragma unroll
    for (int j = 0; j < 6; j++)
#pragma unroll
        for (int k = 0; k < 4; k++) {
            float lm = fmaxf(fmaxf(vals[j][k][0], vals[j][k][1]),
                             fmaxf(vals[j][k][2], vals[j][k][3]));
            pm[(k * 6 + j) * 256 + tid] = (bf16)lm;
        }
    __syncthreads();
#pragma unroll
    for (int s = 0; s < 6; s++) {
        int rid = wv_ * 6 + s;
        bf16x4 p = *reinterpret_cast<const bf16x4*>(&pm[rid * 256 + lane * 4]);
        float mx = fmaxf(fmaxf((float)p[0], (float)p[1]), fmaxf((float)p[2], (float)p[3]));
#pragma unroll
        for (int off = 32; off; off >>= 1) mx = fmaxf(mx, __shfl_xor(mx, off));
        if (lane == 0) mxs[rid] = mx;
    }
    __syncthreads();
#pragma unroll
    for (int j = 0; j < 6; j++)
#pragma unroll
        for (int k = 0; k < 4; k++) {
            int rid = k * 6 + j;
            float mx = mxs[rid];
            float ls = 0.f;
#pragma unroll
            for (int u = 0; u < 4; u++) ls += __expf(vals[j][k][u] - mx);
            pm[rid * 256 + tid] = (bf16)ls;
        }
    __syncthreads();
#pragma unroll
    for (int s = 0; s < 6; s++) {
        int rid = wv_ * 6 + s;
        bf16x4 p = *reinterpret_cast<const bf16x4*>(&pm[rid * 256 + lane * 4]);
        float sm = (float)p[0] + (float)p[1] + (float)p[2] + (float)p[3];
#pragma unroll
        for (int off = 32; off; off >>= 1) sm += __shfl_xor(sm, off);
        if (lane == 0) rsum[rid] = sm;
    }
    __syncthreads();

    // ---- gate & stage to sG (invalid rows stay zero) ----
#pragma unroll
    for (int j = 0; j < 6; j++) {
        int nm = n0 - 1 + j;
        bool valid = (nm >= 0 && nm < 1024);
#pragma unroll
        for (int k = 0; k < 4; k++) {
            int rid = k * 6 + j;
            float mx = mxs[rid], ri = 1.0f / rsum[rid];
            bf16x4 g4;
#pragma unroll
            for (int u = 0; u < 4; u++) {
                float t = vals[j][k][u];
                g4[u] = valid ? (bf16)(t * __expf(t - mx) * ri) : (bf16)0.0f;
            }
            *reinterpret_cast<bf16x4*>(&sG[rid * 1024 + m0]) = g4;
        }
    }
    __syncthreads();

    // ---- conv1 (4->1) on gated rows ----
    float acc1[4][4] = {};
    for (int c = 0; c < 4; c++) {
        float rv2[6][6];
#pragma unroll
        for (int j = 0; j < 6; j++) {
            const bf16* gp = &sG[(c * 6 + j) * 1024];
            bf16x4 t4 = *reinterpret_cast<const bf16x4*>(gp + m0);
#pragma unroll
            for (int u = 0; u < 4; u++) rv2[j][1 + u] = (float)t4[u];
            rv2[j][0] = (m0 > 0)        ? (float)gp[m0 - 1] : 0.f;
            rv2[j][5] = (m0 + 4 < 1024) ? (float)gp[m0 + 4] : 0.f;
        }
#pragma unroll
        for (int r = 0; r < 3; r++) {
            float w3[3];
#pragma unroll
            for (int d = 0; d < 3; d++) w3[d] = w1s[(c * 3 + r) * 3 + d];
#pragma unroll
            for (int i = 0; i < 4; i++)
#pragma unroll
                for (int d = 0; d < 3; d++)
#pragma unroll
                    for (int u = 0; u < 4; u++)
                        acc1[i][u] += w3[d] * rv2[i + r][u + d];
        }
    }
    // ---- write aws (bf16) + final out1 (flag dtype) ----
    const bool f32o = (*nf > NANTHRESH);
    bf16* awsb = aws + (long long)b * 1048576;
#pragma unroll
    for (int i = 0; i < 4; i++) {
        int n = n0 + i;
        bf16x4 o4;
#pragma unroll
        for (int u = 0; u < 4; u++) o4[u] = (bf16)acc1[i][u];
        *reinterpret_cast<bf16x4*>(&awsb[(long long)n * 1024 + m0]) = o4;
        long long fo = 2097152LL + (long long)b * 1048576 + (long long)n * 1024 + m0;
        if (f32o) {
            f32x4 of = {acc1[i][0], acc1[i][1], acc1[i][2], acc1[i][3]};
            *reinterpret_cast<f32x4*>(&((float*)dout)[fo]) = of;
        } else {
            *reinterpret_cast<bf16x4*>(&((bf16*)dout)[fo]) = o4;
        }
    }
}

// ---------------------------------------------------------------------------
// im2col: src [B][N][C] -> dst [B][N][C*9] (k = ci*9 + t)
// ---------------------------------------------------------------------------
__global__ __launch_bounds__(256) void k_im2col(
    const bf16* __restrict__ src, bf16* __restrict__ dst)
{
    const int blk = blockIdx.x;
    const int b = blk >> 10, n = blk & 1023;
    const int h = n >> 5, w = n & 31;
    const int ci = threadIdx.x;
    const bf16* sb = src + (long long)b * 262144;
    bf16* db = dst + ((long long)b * 1024 + n) * 2304 + ci * 9;
#pragma unroll
    for (int dh = 0; dh < 3; dh++)
#pragma unroll
        for (int dw_ = 0; dw_ < 3; dw_++) {
            int hh = h + dh - 1, ww = w + dw_ - 1;
            bf16 vv = (bf16)0.0f;
            if (hh >= 0 && hh < 32 && ww >= 0 && ww < 32)
                vv = sb[(hh * 32 + ww) * 256 + ci];
            db[dh * 3 + dw_] = vv;
        }
}

extern "C" void kernel_launch(void* const* d_in, const int* in_sizes, int n_in,
                              void* d_out, int out_size, void* d_ws, size_t ws_size,
                              hipStream_t stream)
{
    bf16* ws = (bf16*)d_ws;
    int* flagp = (int*)(ws + FLAG_ELOFF);

    bf16* cw      = ws + CW_OFF;
    bf16* cx      = ws + CX_OFF;
    bf16* dwq     = ws + DWQ_OFF;
    bf16* dwk     = ws + DWK_OFF;
    bf16* dwv     = ws + DWV_OFF;
    bf16* qT      = ws + QT_OFF;
    bf16* kT      = ws + KT_OFF;
    bf16* v       = ws + V_OFF;
    bf16* aws     = ws + AWS_OFF;
    bf16* att     = ws + ATT_OFF;
    bf16* outp    = ws + OUTP_OFF;
    bf16* colbuf  = ws + COL_OFF;

    bf16* c_qa_dw_w = cw + 0;      bf16* c_qa_dw_b = cw + 2304;
    bf16* c_qa_pw_w = cw + 2560;   bf16* c_qa_pw_b = cw + 68096;
    bf16* c_ka_dw_w = cw + 68352;  bf16* c_ka_dw_b = cw + 70656;
    bf16* c_ka_pw_w = cw + 70912;  bf16* c_ka_pw_b = cw + 333056;
    bf16* c_va_dw_w = cw + 334080; bf16* c_va_dw_b = cw + 336384;
    bf16* c_va_pw_w = cw + 336640; bf16* c_va_pw_b = cw + 402176;
    bf16* c_attn0   = cw + 402432;
    bf16* c_bn_g    = cw + 402576; bf16* c_bn_b = cw + 402580;
    bf16* c_bn_m    = cw + 402584; bf16* c_bn_v = cw + 402588;
    bf16* c_attn1   = cw + 402592;
    bf16* c_proj    = cw + 402640;

    // 0) dtype detect + normalize inputs to bf16
    k_zero<<<1, 64, 0, stream>>>(flagp);
    k_detect<<<64, 256, 0, stream>>>((const unsigned short*)d_in[0], flagp);
    SrcPtrs sp;
    for (int i = 0; i < 20; i++) sp.p[i] = d_in[i];
    k_convert<<<dim3(256, 20), 256, 0, stream>>>(sp, ws, flagp);

    // 1) depthwise convs (transposed outputs)
    k_dw<<<dim3(4, 16, 8), 256, 0, stream>>>(cx, c_qa_dw_w, c_qa_dw_b, c_ka_dw_w, c_ka_dw_b,
                                             c_va_dw_w, c_va_dw_b, dwq, dwk, dwv);
    // 2) pointwise GEMMs
    gemm_nt<<<dim3(4, 128, 1), 256, 0, stream>>>(dwq, c_qa_pw_w, c_qa_pw_b, qT,
        256, 256, 256, 256, 1, 0, 0, 0, 0, 0, 0, 1.0f, 2, flagp, 0);
    gemm_nt<<<dim3(16, 128, 1), 256, 0, stream>>>(dwk, c_ka_pw_w, c_ka_pw_b, kT,
        256, 256, 256, 1024, 1, 0, 0, 0, 0, 0, 0, 1.0f, 2, flagp, 0);
    gemm_nt<<<dim3(128, 4, 1), 256, 0, stream>>>(c_va_pw_w, dwv, c_va_pw_b, v,
        256, 256, 256, 8192, 1, 0, 0, 0, 0, 0, 0, 1.0f, 1, flagp, 0);
    // 3) attn = scale * q^T k, full batch: z = b*4+kk
    gemm_nt<<<dim3(16, 16, 32), 256, 0, stream>>>(qT, kT, nullptr, att,
        256, 256, 1024, 1024,
        4, 262144LL, 0LL, 1048576LL, 256LL, 4194304LL, 1048576LL,
        0.0625f, 0, flagp, 0);
    // 4+5) fused conv4->4 + BN + gating + conv4->1  -> aws + out1
    k_midconv<<<dim3(256, 8), 256, 0, stream>>>(att, c_attn0, c_bn_g, c_bn_b, c_bn_m, c_bn_v,
                                                c_attn1, aws, d_out, flagp);
    // 6) outp[b][n][c] = sum_m aws[b][n][m] * v[c][b*1024+m]
    gemm_nt<<<dim3(4, 16, 8), 256, 0, stream>>>(aws, v, nullptr, outp,
        1024, 1024, 8192, 256,
        1, 1048576LL, 0LL, 1024LL, 0LL, 262144LL, 0LL, 1.0f, 0, flagp, 0);
    // 7) proj conv: im2col + GEMM -> out0 (flag dtype)
    k_im2col<<<8192, 256, 0, stream>>>(outp, colbuf);
    gemm_nt<<<dim3(16, 4, 8), 256, 0, stream>>>(c_proj, colbuf, nullptr, d_out,
        2304, 2304, 2304, 1024,
        1, 0LL, 0LL, 2359296LL, 0LL, 262144LL, 0LL, 1.0f, 0, flagp, 1);
}